// Round 5
// baseline (421.130 us; speedup 1.0000x reference)
//
#include <hip/hip_runtime.h>

typedef unsigned int u32;
typedef _Float16 h2v __attribute__((ext_vector_type(2)));
typedef _Float16 h4v __attribute__((ext_vector_type(4)));
typedef float f4v __attribute__((ext_vector_type(4)));
struct u32x2 { u32 x, y; };

namespace {

constexpr int kB = 256, kT = 1024, kS = 96, kStart = 1;
constexpr float kCF = 3.5f;
constexpr float kLn2 = 0.69314718055994531f;
constexpr int kNT = 16;                    // batch tiles of 16
constexpr int kSlotU = 832;                // u32 per (bt,t) slot: 768 EF + 64 mask
constexpr int kNSlots = kNT * kT;          // 16384
constexpr size_t kEFGu = (size_t)kNSlots * kSlotU;
// f32-unit offsets into ws after the EF table
constexpr size_t OPF  = kEFGu;
constexpr size_t OWB  = OPF + (size_t)kB * kS;
constexpr size_t OLF  = OWB + (size_t)kB * kS;
constexpr size_t OLB  = OLF + kB;
constexpr size_t ONUM = OLB + kB;
constexpr size_t OMS  = ONUM + kB;
constexpr size_t kNeedBytes = (OMS + kB) * 4;

__device__ __forceinline__ u32 pkmul(u32 a, u32 b) {
  u32 d; asm("v_pk_mul_f16 %0, %1, %2" : "=v"(d) : "v"(a), "v"(b)); return d;
}
__device__ __forceinline__ u32 pkmax(u32 a, u32 b) {
  u32 d; asm("v_pk_max_f16 %0, %1, %2" : "=v"(d) : "v"(a), "v"(b)); return d;
}
__device__ __forceinline__ u32 pkrtz(float a, float b) {
  return __builtin_bit_cast(u32, __builtin_amdgcn_cvt_pkrtz(a, b));
}
__device__ __forceinline__ h4v mkh4(u32 a, u32 b) {
  u32x2 t{a, b}; return __builtin_bit_cast(h4v, t);
}

// per-column (batch) renorm: exact power-of-2 scale toward max-exponent 11
__device__ __forceinline__ void renorm(u32 (&B)[6][2], float& Lacc) {
  u32 m = B[0][0];
#pragma unroll
  for (int kt = 0; kt < 6; ++kt)
#pragma unroll
    for (int pr = 0; pr < 2; ++pr)
      if (kt | pr) m = pkmax(m, B[kt][pr]);
  m = pkmax(m, (u32)__shfl_xor((int)m, 16, 64));
  m = pkmax(m, (u32)__shfl_xor((int)m, 32, 64));
  m = pkmax(m, (m >> 16) | (m << 16));
  int e = (int)((m >> 10) & 31);
  e = e < 1 ? 1 : (e > 25 ? 25 : e);
  u32 sb = (u32)(26 - e) << 10;  // fp16 2^(11-e), exact
  sb |= sb << 16;
#pragma unroll
  for (int kt = 0; kt < 6; ++kt)
#pragma unroll
    for (int pr = 0; pr < 2; ++pr) B[kt][pr] = pkmul(B[kt][pr], sb);
  Lacc += (float)(e - 11) * kLn2;
}

// ---------------- prep: EF table (fp16, MFMA C/B-fragment order) + numerator ----------------
__global__ __launch_bounds__(256) void crf_prep(
    const float* __restrict__ F, const int* __restrict__ states,
    const float* __restrict__ mask, const float* __restrict__ trans,
    u32* __restrict__ efg, float* __restrict__ ws) {
  __shared__ float red[256];
  const int blk = blockIdx.x;
  const int tid = threadIdx.x;
  if (blk < kNSlots) {
    const int bt = blk >> 10, t = blk & 1023;
    u32* out = efg + (size_t)blk * kSlotU;
#pragma unroll
    for (int qq = 0; qq < 4; ++qq) {
      const int c = qq * 256 + tid;
      if (c < 768) {
        const int ll = c / 12, j = c % 12;
        const int col = ll & 15, q4 = (ll >> 4) * 4;
        const int s0 = (j >> 1) * 16 + q4 + (j & 1) * 2;
        const int b = bt * 16 + col;
        const float2 fv = *(const float2*)(F + ((size_t)b * kT + t) * kS + s0);
        out[c] = pkrtz(__expf(fv.x - kCF), __expf(fv.y - kCF));
      } else if (c < kSlotU) {
        const int col = (c - 768) & 15;
        out[c] = (mask[(size_t)(bt * 16 + col) * kT + t] > 0.f) ? ~0u : 0u;
      }
    }
    return;
  }
  // numerator + mask-count for the bt batch-block
  const int b = blk - kNSlots;
  const int* st = states + b * kT;
  const float* Fb = F + (size_t)b * kT * kS;
  const float* mb = mask + b * kT;
  float acc = 0.f, msum = 0.f;
  for (int t = tid; t < kT; t += 256) {
    const int cu = st[t];
    const int pr = (t > 0) ? st[t - 1] : kStart;
    const float mk = mb[t];
    acc += (Fb[(size_t)t * kS + cu] + trans[cu * kS + pr]) * mk;
    msum += mk;
  }
  red[tid] = acc;
  __syncthreads();
  if (tid < 128) red[tid] += red[tid + 128];
  __syncthreads();
  if (tid < 64) {
    float v = red[tid] + red[tid + 64];
#pragma unroll
    for (int off = 32; off > 0; off >>= 1) v += __shfl_xor(v, off, 64);
    if (tid == 0) ws[ONUM + b] = v;
  }
  __syncthreads();
  red[tid] = msum;
  __syncthreads();
  if (tid < 128) red[tid] += red[tid + 128];
  __syncthreads();
  if (tid < 64) {
    float v = red[tid] + red[tid + 64];
#pragma unroll
    for (int off = 32; off > 0; off >>= 1) v += __shfl_xor(v, off, 64);
    if (tid == 0) ws[OMS + b] = v;
  }
}

// ---------------- chains: blocks [0,16) fwd, [16,32) bwd; wave0 = chain, waves1-2 = loaders --
__global__ __launch_bounds__(192, 1) void crf_chains(
    const u32* __restrict__ efg, const float* __restrict__ trans,
    float* __restrict__ ws) {
  const int bid = blockIdx.x;
  const bool bwd = bid >= kNT;
  const int bt = bwd ? bid - kNT : bid;
  const int tid = threadIdx.x, wid = tid >> 6, l = tid & 63;
  __shared__ u32 ring[24 * kSlotU];   // 24-slot ring, 3 windows of 8 steps
  const u32* tbase = efg + (size_t)bt * kT * kSlotU;

  if (wid != 0) {  // ---- loader waves ----
    const int par = wid - 1;
    auto loadwin = [&](int w) {
      for (int j = par; j < 8; j += 2) {
        const int u = w * 8 + j;
        const int t = bwd ? (kT - 1 - u) : u;
        const uint4* src = (const uint4*)(tbase + (size_t)t * kSlotU);
        uint4* dst = (uint4*)(ring + (u % 24) * kSlotU);
#pragma unroll
        for (int qq = 0; qq < 4; ++qq) {
          const int c = qq * 64 + l;
          if (c < kSlotU / 4) dst[c] = src[c];
        }
      }
    };
    loadwin(0); loadwin(1);
    __syncthreads();
    for (int k = 0; k < 64; ++k) {
      if (k + 2 < 64) loadwin(k + 2);
      __syncthreads();
    }
    return;
  }

  // ---- chain wave ----
  const int r = l & 15, q4 = (l >> 4) * 4;
  h4v A[6][6];   // M (fwd) or M^T (bwd) tiles, fp16, A-fragment layout
#pragma unroll
  for (int it = 0; it < 6; ++it)
#pragma unroll
    for (int kt = 0; kt < 6; ++kt) {
      float m0, m1, m2, m3;
      if (!bwd) {
        const float* tp = trans + (it * 16 + r) * kS + kt * 16 + q4;
        m0 = tp[0]; m1 = tp[1]; m2 = tp[2]; m3 = tp[3];
      } else {
        const float* tp = trans + (kt * 16 + q4) * kS + it * 16 + r;
        m0 = tp[0]; m1 = tp[kS]; m2 = tp[2 * kS]; m3 = tp[3 * kS];
      }
      A[it][kt] = mkh4(pkrtz(__expf(m0 - kCF), __expf(m1 - kCF)),
                       pkrtz(__expf(m2 - kCF), __expf(m3 - kCF)));
    }

  u32 B[6][2];   // state vector, fp16 pairs, B/C-fragment layout
#pragma unroll
  for (int kt = 0; kt < 6; ++kt) {
    B[kt][0] = bwd ? 0x3C003C00u : 0u;
    B[kt][1] = bwd ? 0x3C003C00u : 0u;
  }
  if (!bwd && l < 16) B[0][0] = 0x3C000000u;  // p0: state 1 (=high half of pair {0,1})

  float Lacc = 0.f;
  __syncthreads();  // windows 0,1 staged

  const u32* sp = ring + l * 12;
  uint4 e0 = ((const uint4*)sp)[0], e1 = ((const uint4*)sp)[1], e2 = ((const uint4*)sp)[2];
  u32 mw = ring[768 + l];

  for (int k = 0; k < 64; ++k) {
#pragma unroll 2
    for (int j = 0; j < 8; ++j) {
      const int u = k * 8 + j;
      const int un = (u < 511) ? u + 1 : 511;
      const u32* sn = ring + (un % 24) * kSlotU + l * 12;
      const uint4 f0 = ((const uint4*)sn)[0];
      const uint4 f1 = ((const uint4*)sn)[1];
      const uint4 f2 = ((const uint4*)sn)[2];
      const u32 mn = ring[(un % 24) * kSlotU + 768 + l];
      const u32 ef[12] = {e0.x, e0.y, e0.z, e0.w, e1.x, e1.y, e1.z, e1.w,
                          e2.x, e2.y, e2.z, e2.w};

      u32 Bu[6][2];
#pragma unroll
      for (int kt = 0; kt < 6; ++kt)
#pragma unroll
        for (int pr = 0; pr < 2; ++pr)
          Bu[kt][pr] = bwd ? pkmul(B[kt][pr], ef[kt * 2 + pr]) : B[kt][pr];

      f4v C[6];
#pragma unroll
      for (int it = 0; it < 6; ++it) C[it] = f4v{0.f, 0.f, 0.f, 0.f};
#pragma unroll
      for (int kt = 0; kt < 6; ++kt) {
        const h4v bk = mkh4(Bu[kt][0], Bu[kt][1]);
#pragma unroll
        for (int it = 0; it < 6; ++it)
          C[it] = __builtin_amdgcn_mfma_f32_16x16x16f16(A[it][kt], bk, C[it], 0, 0, 0);
      }
#pragma unroll
      for (int it = 0; it < 6; ++it)
#pragma unroll
        for (int pr = 0; pr < 2; ++pr) {
          u32 cand = pkrtz(C[it][2 * pr], C[it][2 * pr + 1]);
          if (!bwd) cand = pkmul(cand, ef[it * 2 + pr]);
          B[it][pr] = mw ? cand : B[it][pr];
        }
      if (u & 1) renorm(B, Lacc);
      e0 = f0; e1 = f1; e2 = f2; mw = mn;
    }
    __syncthreads();
  }

  float* dst = ws + (bwd ? OWB : OPF) + ((size_t)bt * 16 + (l & 15)) * kS;
#pragma unroll
  for (int kt = 0; kt < 6; ++kt)
#pragma unroll
    for (int pr = 0; pr < 2; ++pr) {
      const h2v hv = __builtin_bit_cast(h2v, B[kt][pr]);
      const int s0 = kt * 16 + q4 + pr * 2;
      dst[s0] = (float)hv[0];
      dst[s0 + 1] = (float)hv[1];
    }
  if (l < 16) ws[(bwd ? OLB : OLF) + bt * 16 + l] = Lacc;
}

// ---------------- finalize ----------------
__global__ __launch_bounds__(64) void crf_fin(
    const float* __restrict__ ws, float* __restrict__ out) {
  const int b = blockIdx.x, l = threadIdx.x;
  float d = ws[OPF + (size_t)b * kS + l] * ws[OWB + (size_t)b * kS + l];
  if (l < 32) d += ws[OPF + (size_t)b * kS + 64 + l] * ws[OWB + (size_t)b * kS + 64 + l];
#pragma unroll
  for (int off = 32; off; off >>= 1) d += __shfl_xor(d, off, 64);
  if (l == 0)
    out[b] = (ws[OLF + b] + ws[OLB + b] + logf(d) + 2.f * kCF * ws[OMS + b]) - ws[ONUM + b];
}

// ================= fallback path (R3, known-good) if ws is too small =================
constexpr int FB_PF = 0;
constexpr int FB_LF = kB * kS;
constexpr int FB_WB = FB_LF + kB;
constexpr int FB_LB = FB_WB + kB * kS;

__device__ __forceinline__ void renorm96(const float4* pv, float& pnew, float& Lacc) {
  float4 m4 = pv[0];
#pragma unroll
  for (int k = 1; k < 12; ++k) {
    m4.x = fmaxf(m4.x, pv[k].x); m4.y = fmaxf(m4.y, pv[k].y);
    m4.z = fmaxf(m4.z, pv[k].z); m4.w = fmaxf(m4.w, pv[k].w);
  }
  float m = fmaxf(fmaxf(m4.x, m4.y), fmaxf(m4.z, m4.w));
  m = fmaxf(m, __shfl_xor(m, 1, 64));
  const int e = (__float_as_int(m) >> 23) & 0xFF;
  const float scale = __int_as_float((254 - e) << 23);
  Lacc += (float)(e - 127) * kLn2;
  pnew *= scale;
}

__global__ __launch_bounds__(192) void fb_halves(
    const float* __restrict__ F, const float* __restrict__ mask,
    const float* __restrict__ trans, float* __restrict__ ws) {
  const bool bwd = blockIdx.x >= kB;
  const int b = bwd ? (blockIdx.x - kB) : blockIdx.x;
  const int tid = threadIdx.x;
  const int h = tid & 1;
  const int i = tid >> 1;
  __shared__ __align__(16) float pbuf[2][kS];
  __shared__ __align__(16) float fl[2][16 * kS];
  __shared__ __align__(16) float ml[kT];
  const float* Fb = F + (size_t)b * kT * kS;
  float mwv[48];
  if (!bwd) {
    const float4* tp = (const float4*)(trans + i * kS + h * 48);
#pragma unroll
    for (int k = 0; k < 12; ++k) {
      const float4 tv = tp[k];
      mwv[4 * k + 0] = __expf(tv.x - kCF); mwv[4 * k + 1] = __expf(tv.y - kCF);
      mwv[4 * k + 2] = __expf(tv.z - kCF); mwv[4 * k + 3] = __expf(tv.w - kCF);
    }
  } else {
#pragma unroll
    for (int k = 0; k < 48; ++k) mwv[k] = __expf(trans[(h * 48 + k) * kS + i] - kCF);
  }
  const int gb0 = bwd ? (kT - 16) : 0;
  const int gstep = bwd ? -16 : 16;
  {
    const float4* s = (const float4*)(Fb + (size_t)gb0 * kS + tid * 8);
    const float4 a = s[0], c4 = s[1];
    *(float4*)&fl[0][tid * 8] = a;
    *(float4*)&fl[0][tid * 8 + 4] = c4;
    const float4* mb4 = (const float4*)(mask + (size_t)b * kT);
    for (int idx = tid; idx < kT / 4; idx += 192) ((float4*)ml)[idx] = mb4[idx];
    if (!bwd && h == 0) pbuf[0][i] = (i == kStart) ? 1.0f : 0.0f;
  }
  __syncthreads();
  float Lacc = 0.0f;
  float pown = bwd ? 1.0f : ((i == kStart) ? 1.0f : 0.0f);
  int cur = 0;
  float4 pfa, pfb;
  for (int tc = 0; tc < 32; ++tc) {
    const int fbuf = tc & 1;
    if (tc < 31) {
      const float4* s = (const float4*)(Fb + (size_t)(gb0 + (tc + 1) * gstep) * kS + tid * 8);
      pfa = s[0]; pfb = s[1];
    }
#pragma unroll
    for (int tt = 0; tt < 16; ++tt) {
      const int tl = tc * 16 + tt;
      const int t = bwd ? (kT - 1 - tl) : tl;
      const float f = fl[fbuf][(bwd ? (15 - tt) : tt) * kS + i];
      const float mkv = ml[t];
      if (!bwd) {
        const float* pc = &pbuf[cur][h * 48];
        float4 pv[12];
#pragma unroll
        for (int k = 0; k < 12; ++k) pv[k] = ((const float4*)pc)[k];
        float a0 = 0.f, a1 = 0.f, a2 = 0.f, a3 = 0.f;
#pragma unroll
        for (int k = 0; k < 12; ++k) {
          a0 = fmaf(mwv[4 * k + 0], pv[k].x, a0); a1 = fmaf(mwv[4 * k + 1], pv[k].y, a1);
          a2 = fmaf(mwv[4 * k + 2], pv[k].z, a2); a3 = fmaf(mwv[4 * k + 3], pv[k].w, a3);
        }
        float acc = (a0 + a1) + (a2 + a3);
        acc += __shfl_xor(acc, 1, 64);
        float pnew = (mkv > 0.f) ? acc * __expf(f - kCF) : pown;
        if (((tt + 1) & 7) == 0) renorm96(pv, pnew, Lacc);
        if (tt == 15 && tc < 31) {
          *(float4*)&fl[fbuf ^ 1][tid * 8] = pfa;
          *(float4*)&fl[fbuf ^ 1][tid * 8 + 4] = pfb;
        }
        if (h == 0) pbuf[cur ^ 1][i] = pnew;
        __syncthreads();
        pown = pnew;
      } else {
        const float uu = pown * __expf(f - kCF);
        if (h == 0) pbuf[cur ^ 1][i] = uu;
        if (tt == 15 && tc < 31) {
          *(float4*)&fl[fbuf ^ 1][tid * 8] = pfa;
          *(float4*)&fl[fbuf ^ 1][tid * 8 + 4] = pfb;
        }
        __syncthreads();
        const float* pc = &pbuf[cur ^ 1][h * 48];
        float4 pv[12];
#pragma unroll
        for (int k = 0; k < 12; ++k) pv[k] = ((const float4*)pc)[k];
        float a0 = 0.f, a1 = 0.f, a2 = 0.f, a3 = 0.f;
#pragma unroll
        for (int k = 0; k < 12; ++k) {
          a0 = fmaf(mwv[4 * k + 0], pv[k].x, a0); a1 = fmaf(mwv[4 * k + 1], pv[k].y, a1);
          a2 = fmaf(mwv[4 * k + 2], pv[k].z, a2); a3 = fmaf(mwv[4 * k + 3], pv[k].w, a3);
        }
        float acc = (a0 + a1) + (a2 + a3);
        acc += __shfl_xor(acc, 1, 64);
        float pnew = (mkv > 0.f) ? acc : pown;
        if (((tt + 1) & 7) == 0) renorm96(pv, pnew, Lacc);
        pown = pnew;
      }
      cur ^= 1;
    }
  }
  if (h == 0) ws[(bwd ? FB_WB : FB_PF) + b * kS + i] = pown;
  if (tid == 0) ws[(bwd ? FB_LB : FB_LF) + b] = Lacc;
}

__global__ __launch_bounds__(256) void fb_finalize(
    const float* __restrict__ F, const int* __restrict__ states,
    const float* __restrict__ mask, const float* __restrict__ trans,
    const float* __restrict__ ws, float* __restrict__ out) {
  const int b = blockIdx.x;
  const int tid = threadIdx.x;
  const int* st = states + b * kT;
  const float* Fb = F + (size_t)b * kT * kS;
  const float* mb = mask + b * kT;
  float acc = 0.f;
  for (int t = tid; t < kT; t += 256) {
    const int cu = st[t];
    const int pr = (t > 0) ? st[t - 1] : kStart;
    acc += (Fb[(size_t)t * kS + cu] + trans[cu * kS + pr]) * mb[t];
  }
  __shared__ float red[256];
  red[tid] = acc;
  __syncthreads();
  if (tid < 128) red[tid] += red[tid + 128];
  __syncthreads();
  float numv = 0.f;
  if (tid < 64) {
    float v = red[tid] + red[tid + 64];
#pragma unroll
    for (int off = 32; off > 0; off >>= 1) v += __shfl_xor(v, off, 64);
    numv = v;
  }
  __syncthreads();
  float dv = 0.f;
  if (tid < kS) dv = ws[FB_PF + b * kS + tid] * ws[FB_WB + b * kS + tid];
  red[tid] = dv;
  __syncthreads();
  if (tid < 128) red[tid] += red[tid + 128];
  __syncthreads();
  if (tid < 64) {
    float v = red[tid] + red[tid + 64];
#pragma unroll
    for (int off = 32; off > 0; off >>= 1) v += __shfl_xor(v, off, 64);
    if (tid == 0) out[b] = (ws[FB_LF + b] + ws[FB_LB + b] + logf(v)) - numv;
  }
}

}  // namespace

extern "C" void kernel_launch(void* const* d_in, const int* in_sizes, int n_in,
                              void* d_out, int out_size, void* d_ws, size_t ws_size,
                              hipStream_t stream) {
  const float* F      = (const float*)d_in[0];
  const int*   states = (const int*)d_in[1];
  const float* mask   = (const float*)d_in[2];
  const float* trans  = (const float*)d_in[3];
  float* out = (float*)d_out;
  if (ws_size >= kNeedBytes) {
    hipLaunchKernelGGL(crf_prep, dim3(kNSlots + kB), dim3(256), 0, stream,
                       F, states, mask, trans, (u32*)d_ws, (float*)d_ws);
    hipLaunchKernelGGL(crf_chains, dim3(2 * kNT), dim3(192), 0, stream,
                       (const u32*)d_ws, trans, (float*)d_ws);
    hipLaunchKernelGGL(crf_fin, dim3(kB), dim3(64), 0, stream,
                       (const float*)d_ws, out);
  } else {
    float* ws = (float*)d_ws;
    hipLaunchKernelGGL(fb_halves, dim3(2 * kB), dim3(192), 0, stream, F, mask, trans, ws);
    hipLaunchKernelGGL(fb_finalize, dim3(kB), dim3(256), 0, stream,
                       F, states, mask, trans, ws, out);
  }
}